// Round 11
// baseline (341.437 us; speedup 1.0000x reference)
//
#include <hip/hip_runtime.h>

#define IN_DIM 4096
#define OUT_DIM 4096
#define M_DIM 8192
#define RANK 32
#define BK 32
#define NT (IN_DIM / BK)   // 128 K-tiles

typedef __bf16 bf16x8 __attribute__((ext_vector_type(8)));
typedef float f32x4 __attribute__((ext_vector_type(4)));

__device__ __forceinline__ unsigned short f2bf(float f) {
  unsigned u = __builtin_bit_cast(unsigned, f);
  u += 0x7FFF + ((u >> 16) & 1);   // round-to-nearest-even
  return (unsigned short)(u >> 16);
}

// ---------------- fused prep: blocks [0,1024) do Wb, [1024,1536) do Xb ----------------
__global__ __launch_bounds__(256) void prep_kernel(
    const float* __restrict__ X, unsigned short* __restrict__ Xb,
    const float* __restrict__ W, const float* __restrict__ A,
    const float* __restrict__ B, unsigned short* __restrict__ Wb) {
  const int tid = threadIdx.x;
  if (blockIdx.x >= 1024) {
    const int idx0 = (blockIdx.x - 1024) * 256 + tid;
    const int stride = 512 * 256;
    const int total4 = (M_DIM * IN_DIM) / 4;
    for (int i = idx0; i < total4; i += stride) {
      const float4 v = reinterpret_cast<const float4*>(X)[i];
      ushort4 o;
      o.x = f2bf(v.x); o.y = f2bf(v.y); o.z = f2bf(v.z); o.w = f2bf(v.w);
      reinterpret_cast<ushort4*>(Xb)[i] = o;
    }
    return;
  }
  __shared__ unsigned short sA[128][40];
  __shared__ unsigned short sB[128][40];
  const int lane = tid & 63;
  const int wid  = tid >> 6;
  const int wr   = wid >> 1, wc = wid & 1;
  const int li   = lane & 15, kg = lane >> 4;
  const int bRow = (blockIdx.x >> 5) * 128;   // out dim
  const int bCol = (blockIdx.x & 31) * 128;   // in dim

  for (int i = tid; i < 128 * 8; i += 256) {
    const int r = i >> 3, q = i & 7;
    const float4 va = reinterpret_cast<const float4*>(A + (size_t)(bRow + r) * RANK)[q];
    ushort4 oa;
    oa.x = f2bf(va.x); oa.y = f2bf(va.y); oa.z = f2bf(va.z); oa.w = f2bf(va.w);
    *reinterpret_cast<ushort4*>(&sA[r][q * 4]) = oa;
    const float4 vb = reinterpret_cast<const float4*>(B + (size_t)(bCol + r) * RANK)[q];
    ushort4 ob;
    ob.x = f2bf(vb.x); ob.y = f2bf(vb.y); ob.z = f2bf(vb.z); ob.w = f2bf(vb.w);
    *reinterpret_cast<ushort4*>(&sB[r][q * 4]) = ob;
  }
  __syncthreads();

  bf16x8 af[4], bq[4];
#pragma unroll
  for (int m = 0; m < 4; ++m)
    af[m] = *reinterpret_cast<const bf16x8*>(&sA[wr * 64 + m * 16 + li][kg * 8]);
#pragma unroll
  for (int n = 0; n < 4; ++n)
    bq[n] = *reinterpret_cast<const bf16x8*>(&sB[wc * 64 + n * 16 + li][kg * 8]);

  f32x4 acc[4][4];
#pragma unroll
  for (int m = 0; m < 4; ++m)
#pragma unroll
    for (int n = 0; n < 4; ++n) {
      acc[m][n] = f32x4{0.f, 0.f, 0.f, 0.f};
      acc[m][n] = __builtin_amdgcn_mfma_f32_16x16x32_bf16(af[m], bq[n], acc[m][n], 0, 0, 0);
    }

#pragma unroll
  for (int m = 0; m < 4; ++m) {
#pragma unroll
    for (int n = 0; n < 4; ++n) {
      const int col = bCol + wc * 64 + n * 16 + li;
#pragma unroll
      for (int j = 0; j < 4; ++j) {
        const int row = bRow + wr * 64 + m * 16 + kg * 4 + j;
        const size_t idx = (size_t)row * IN_DIM + col;
        Wb[idx] = f2bf(W[idx] + acc[m][n][j]);
      }
    }
  }
}

// ---------------- main GEMM: 128x256 tile, BK=32, 3-buf LDS, 2 BLOCKS/CU ----------------
// R6-R10 post-mortem: five scheduling variants all 229-245 us -> within one
// 8-wave lockstep block, LDS (2300 cyc/tile) and MFMA (2484) serialize at each
// barrier regardless of instruction order. This kernel attacks with hardware
// TLP instead: 72 KiB LDS (3 bufs x 24 KiB) + <=128 VGPR -> TWO blocks/CU; when
// block A sits at its barrier / drains LDS, block B's waves issue MFMA (m114:
// co-resident waves overlap pipes at max, not sum). 8 waves (2M x 4N), wave-tile
// 64x64 = 4x4 frags of 16x16x32; one barrier per K-tile window:
//   window t: STAGE(t+2)->buf[(t+2)%3]; rd 4 af + 4 bq from buf[t%3];
//             vmcnt(3) [retire tile t+1]; BAR; 16 MFMA
// vmcnt induction: entering window t outstanding = 3 (tile t+1, issued t-1);
// +3 (t+2) = 6; vmcnt(3) retires exactly tile t+1 (FIFO) -> published at BAR.
// WAR: STAGE(t+2) overwrites buf holding tile t-1, whose reads issued >=1
// barrier + ~300cyc-HBM-latency earlier. Chunk swizzle (4 chunks/32-k row):
// physical chunk = kc ^ ((r>>1)&3); read quad = 4*(li&1)+(kg^((li>>1)&3))
// covers all 8 bank-quads per 8-lane group -> 2-way max (free, m136).
__global__ __launch_bounds__(512, 4) void gemm_kernel(
    const unsigned short* __restrict__ Xb, const unsigned short* __restrict__ Wb,
    const float* __restrict__ bias, float* __restrict__ Y) {
  __shared__ unsigned short lds[3 * 12288];   // 72 KiB: 3 x (A 128x32 + B 256x32)
  const int tid  = threadIdx.x;
  const int lane = tid & 63;
  const int wid  = tid >> 6;          // 0..7
  const int wr   = wid >> 2;          // 0..1 -> M half
  const int wc   = wid & 3;           // 0..3 -> N quarter
  const int li   = lane & 15, kg = lane >> 4;

  // XCD-aware bijective swizzle: 1024 blocks = 8 XCDs x 128; bx-major within
  // chunk so consecutive blocks share the A panel (L2/L3 locality).
  const int bid = blockIdx.x;
  const int swz = (bid & 7) * 128 + (bid >> 3);
  const int bx  = swz & 15;           // N tiles: 4096/256 = 16
  const int by  = swz >> 4;           // M tiles: 8192/128 = 64
  const int bRow = by * 128, bCol = bx * 256;

  // staging source: thread tid covers physical 16B chunk p (4 chunks/row);
  // row r = p>>2, logical kc = (p&3) ^ ((r>>1)&3)
  const int rS  = tid >> 2;
  const int kcS = (tid & 3) ^ ((rS >> 1) & 3);
  const unsigned short* srcA0 = Xb + (size_t)(bRow + rS) * IN_DIM + kcS * 8;
  const unsigned short* srcB0 = Wb + (size_t)(bCol + rS) * IN_DIM + kcS * 8;
  const unsigned short* srcB1 = srcB0 + (size_t)128 * IN_DIM;
  char* const ldsRaw = (char*)&lds[0];

#define GLD(src, dstoff)                                                       \
  __builtin_amdgcn_global_load_lds(                                            \
      (const __attribute__((address_space(1))) unsigned int*)(src),            \
      (__attribute__((address_space(3))) unsigned int*)(ldsRaw + (dstoff)),    \
      16, 0, 0)
// buffer layout (bytes): A region [0,8192), B region [8192,24576)
#define STAGE(s, base_)                                                        \
  do {                                                                         \
    GLD(srcA0 + (s) * BK, (base_) + tid * 16);                                 \
    GLD(srcB0 + (s) * BK, (base_) + 8192 + tid * 16);                          \
    GLD(srcB1 + (s) * BK, (base_) + 16384 + tid * 16);                         \
  } while (0)
#define BAR() __builtin_amdgcn_s_barrier()
// s_waitcnt imm: [3:0] vmcnt, [6:4] expcnt=7, [11:8] lgkmcnt=15
#define VMCNT(n) __builtin_amdgcn_s_waitcnt(0x0F70 | (n))

  // fragment read offsets (shorts): chunk = kg ^ ((li>>1)&3)
  const int kxs  = (kg ^ ((li >> 1) & 3)) * 8;
  const int rdA  = (wr * 64 + li) * 32 + kxs;            // A region
  const int rdB  = 4096 + (wc * 64 + li) * 32 + kxs;     // B region (shorts)

  bf16x8 af[4], bq[4];
  f32x4 acc[4][4];
#pragma unroll
  for (int m = 0; m < 4; ++m)
#pragma unroll
    for (int n = 0; n < 4; ++n) acc[m][n] = f32x4{0.f, 0.f, 0.f, 0.f};

  // ---- prologue: stage tiles 0,1 into bufs 0,1; publish tile 0 ----
  STAGE(0, 0);
  STAGE(1, 24576);
  VMCNT(3);
  BAR();

  int cur = 0;   // buffer index of tile t
  for (int t = 0; t < NT; ++t) {
    int nx = cur + 2; if (nx >= 3) nx -= 3;
    const bool st2 = (t + 2 < NT);
    if (st2) STAGE(t + 2, nx * 24576);
    const unsigned short* base = &lds[cur * 12288];
#pragma unroll
    for (int mf = 0; mf < 4; ++mf)
      af[mf] = *reinterpret_cast<const bf16x8*>(base + rdA + mf * 512);
#pragma unroll
    for (int nf = 0; nf < 4; ++nf)
      bq[nf] = *reinterpret_cast<const bf16x8*>(base + rdB + nf * 512);
    if (st2) VMCNT(3); else VMCNT(0);
    BAR();
    __builtin_amdgcn_s_setprio(1);
#pragma unroll
    for (int mf = 0; mf < 4; ++mf)
#pragma unroll
      for (int nf = 0; nf < 4; ++nf)
        acc[mf][nf] = __builtin_amdgcn_mfma_f32_16x16x32_bf16(
            af[mf], bq[nf], acc[mf][nf], 0, 0, 0);
    __builtin_amdgcn_s_setprio(0);
    if (++cur == 3) cur = 0;
  }
#undef GLD
#undef STAGE
#undef BAR
#undef VMCNT

  // ---- epilogue: C/D layout col = li, row = kg*4 + j (m89-verified) ----
#pragma unroll
  for (int nf = 0; nf < 4; ++nf) {
    const int col = bCol + wc * 64 + nf * 16 + li;
    const float bv = bias[col];
#pragma unroll
    for (int mf = 0; mf < 4; ++mf) {
      const int row0 = bRow + wr * 64 + mf * 16 + kg * 4;
#pragma unroll
      for (int j = 0; j < 4; ++j)
        Y[(size_t)(row0 + j) * OUT_DIM + col] = acc[mf][nf][j] + bv;
    }
  }
}

extern "C" void kernel_launch(void* const* d_in, const int* in_sizes, int n_in,
                              void* d_out, int out_size, void* d_ws, size_t ws_size,
                              hipStream_t stream) {
  const float* x    = (const float*)d_in[0];
  const float* w    = (const float*)d_in[1];
  const float* bias = (const float*)d_in[2];
  const float* A    = (const float*)d_in[3];
  const float* B    = (const float*)d_in[4];
  float* y = (float*)d_out;

  const size_t xb_bytes = (size_t)M_DIM * IN_DIM * 2;          // 64 MiB
  const size_t wb_bytes = (size_t)OUT_DIM * IN_DIM * 2;        // 32 MiB
  if (ws_size < xb_bytes + wb_bytes) return;

  unsigned short* Xb = (unsigned short*)d_ws;
  unsigned short* Wb = (unsigned short*)((char*)d_ws + xb_bytes);

  prep_kernel<<<1536, 256, 0, stream>>>(x, Xb, w, A, B, Wb);
  gemm_kernel<<<(M_DIM / 128) * (OUT_DIM / 256), 512, 0, stream>>>(Xb, Wb, bias, y);
}

// Round 12
// 324.306 us; speedup vs baseline: 1.0528x; 1.0528x over previous
//
#include <hip/hip_runtime.h>

#define IN_DIM 4096
#define OUT_DIM 4096
#define M_DIM 8192
#define RANK 32
#define BK 32
#define NT (IN_DIM / BK)   // 128 K-tiles

typedef __bf16 bf16x8 __attribute__((ext_vector_type(8)));
typedef float f32x4 __attribute__((ext_vector_type(4)));

__device__ __forceinline__ unsigned short f2bf(float f) {
  unsigned u = __builtin_bit_cast(unsigned, f);
  u += 0x7FFF + ((u >> 16) & 1);   // round-to-nearest-even
  return (unsigned short)(u >> 16);
}

// ---------------- fused prep: blocks [0,1024) do Wb, [1024,1536) do Xb ----------------
__global__ __launch_bounds__(256) void prep_kernel(
    const float* __restrict__ X, unsigned short* __restrict__ Xb,
    const float* __restrict__ W, const float* __restrict__ A,
    const float* __restrict__ B, unsigned short* __restrict__ Wb) {
  const int tid = threadIdx.x;
  if (blockIdx.x >= 1024) {
    const int idx0 = (blockIdx.x - 1024) * 256 + tid;
    const int stride = 512 * 256;
    const int total4 = (M_DIM * IN_DIM) / 4;
    for (int i = idx0; i < total4; i += stride) {
      const float4 v = reinterpret_cast<const float4*>(X)[i];
      ushort4 o;
      o.x = f2bf(v.x); o.y = f2bf(v.y); o.z = f2bf(v.z); o.w = f2bf(v.w);
      reinterpret_cast<ushort4*>(Xb)[i] = o;
    }
    return;
  }
  __shared__ unsigned short sA[128][40];
  __shared__ unsigned short sB[128][40];
  const int lane = tid & 63;
  const int wid  = tid >> 6;
  const int wr   = wid >> 1, wc = wid & 1;
  const int li   = lane & 15, kg = lane >> 4;
  const int bRow = (blockIdx.x >> 5) * 128;   // out dim
  const int bCol = (blockIdx.x & 31) * 128;   // in dim

  for (int i = tid; i < 128 * 8; i += 256) {
    const int r = i >> 3, q = i & 7;
    const float4 va = reinterpret_cast<const float4*>(A + (size_t)(bRow + r) * RANK)[q];
    ushort4 oa;
    oa.x = f2bf(va.x); oa.y = f2bf(va.y); oa.z = f2bf(va.z); oa.w = f2bf(va.w);
    *reinterpret_cast<ushort4*>(&sA[r][q * 4]) = oa;
    const float4 vb = reinterpret_cast<const float4*>(B + (size_t)(bCol + r) * RANK)[q];
    ushort4 ob;
    ob.x = f2bf(vb.x); ob.y = f2bf(vb.y); ob.z = f2bf(vb.z); ob.w = f2bf(vb.w);
    *reinterpret_cast<ushort4*>(&sB[r][q * 4]) = ob;
  }
  __syncthreads();

  bf16x8 af[4], bq[4];
#pragma unroll
  for (int m = 0; m < 4; ++m)
    af[m] = *reinterpret_cast<const bf16x8*>(&sA[wr * 64 + m * 16 + li][kg * 8]);
#pragma unroll
  for (int n = 0; n < 4; ++n)
    bq[n] = *reinterpret_cast<const bf16x8*>(&sB[wc * 64 + n * 16 + li][kg * 8]);

  f32x4 acc[4][4];
#pragma unroll
  for (int m = 0; m < 4; ++m)
#pragma unroll
    for (int n = 0; n < 4; ++n) {
      acc[m][n] = f32x4{0.f, 0.f, 0.f, 0.f};
      acc[m][n] = __builtin_amdgcn_mfma_f32_16x16x32_bf16(af[m], bq[n], acc[m][n], 0, 0, 0);
    }

#pragma unroll
  for (int m = 0; m < 4; ++m) {
#pragma unroll
    for (int n = 0; n < 4; ++n) {
      const int col = bCol + wc * 64 + n * 16 + li;
#pragma unroll
      for (int j = 0; j < 4; ++j) {
        const int row = bRow + wr * 64 + m * 16 + kg * 4 + j;
        const size_t idx = (size_t)row * IN_DIM + col;
        Wb[idx] = f2bf(W[idx] + acc[m][n][j]);
      }
    }
  }
}

// ---------------- main GEMM: 128x256 tile, BK=32, 3-buf LDS, 2 blocks/CU,
//                  L2/L3-LOCAL BLOCK MAP ----------------
// R11 post-mortem: 2 blocks/CU achieved (occ 38%) but HBM-bound — FETCH 830 MB
// (B re-swept per by-row, evicted by 128 MB Y stream), hbm 2.75 TB/s = dur.
// Fix is the block->tile map only: XCD p owns bx pair {2p, 2p+1} and sweeps by
// ascending. Per-XCD B working set = 2 panels = 4 MB (own L2; L3 backstop) ->
// B fetched from HBM once (32 MB). The 16 blocks sharing an A panel (fixed by,
// all bx) have near-consecutive bids -> near-simultaneous dispatch -> each 1 MB
// A panel fetched once into L3, shared (A = 64 MB once). HBM time ~30 us << 
// MFMA floor 132 us -> staging waits vanish; LDS-read pipe binds (~81% cap).
// Window t: STAGE(t+2)->buf[(t+2)%3]; rd 4 af + 4 bq from buf[t%3];
//           vmcnt(3) [retires tile t+1]; BAR; 16 MFMA.
// vmcnt induction: entering t outstanding = 3 (t+1); +3 = 6; vmcnt(3) retires
// t+1 (FIFO). WAR: STAGE(t+2) overwrites buf of tile t-1 (reads retired >=1
// barrier earlier). Chunk swizzle: phys chunk = kc ^ ((r>>1)&3), read chunk =
// kg ^ ((li>>1)&3) -> all bank-quads covered per 8-lane group (2-way, free).
__global__ __launch_bounds__(512, 4) void gemm_kernel(
    const unsigned short* __restrict__ Xb, const unsigned short* __restrict__ Wb,
    const float* __restrict__ bias, float* __restrict__ Y) {
  __shared__ unsigned short lds[3 * 12288];   // 72 KiB: 3 x (A 128x32 + B 256x32)
  const int tid  = threadIdx.x;
  const int lane = tid & 63;
  const int wid  = tid >> 6;          // 0..7
  const int wr   = wid >> 2;          // 0..1 -> M half
  const int wc   = wid & 3;           // 0..3 -> N quarter
  const int li   = lane & 15, kg = lane >> 4;

  // L2/L3-local map: XCD p = bid&7 owns bx {2p, 2p+1}; by sweeps ascending.
  // bids sharing an A panel (same by) are near-consecutive -> co-dispatched.
  const int bid = blockIdx.x;
  const int p   = bid & 7;            // XCD (round-robin heuristic)
  const int k   = bid >> 3;           // 0..127 within XCD
  const int bx  = 2 * p + (k & 1);    // N tiles: 4096/256 = 16
  const int by  = k >> 1;             // M tiles: 8192/128 = 64
  const int bRow = by * 128, bCol = bx * 256;

  // staging source: thread tid covers physical 16B chunk p (4 chunks/row);
  // row r = p>>2, logical kc = (p&3) ^ ((r>>1)&3)
  const int rS  = tid >> 2;
  const int kcS = (tid & 3) ^ ((rS >> 1) & 3);
  const unsigned short* srcA0 = Xb + (size_t)(bRow + rS) * IN_DIM + kcS * 8;
  const unsigned short* srcB0 = Wb + (size_t)(bCol + rS) * IN_DIM + kcS * 8;
  const unsigned short* srcB1 = srcB0 + (size_t)128 * IN_DIM;
  char* const ldsRaw = (char*)&lds[0];

#define GLD(src, dstoff)                                                       \
  __builtin_amdgcn_global_load_lds(                                            \
      (const __attribute__((address_space(1))) unsigned int*)(src),            \
      (__attribute__((address_space(3))) unsigned int*)(ldsRaw + (dstoff)),    \
      16, 0, 0)
// buffer layout (bytes): A region [0,8192), B region [8192,24576)
#define STAGE(s, base_)                                                        \
  do {                                                                         \
    GLD(srcA0 + (s) * BK, (base_) + tid * 16);                                 \
    GLD(srcB0 + (s) * BK, (base_) + 8192 + tid * 16);                          \
    GLD(srcB1 + (s) * BK, (base_) + 16384 + tid * 16);                         \
  } while (0)
#define BAR() __builtin_amdgcn_s_barrier()
// s_waitcnt imm: [3:0] vmcnt, [6:4] expcnt=7, [11:8] lgkmcnt=15
#define VMCNT(n) __builtin_amdgcn_s_waitcnt(0x0F70 | (n))

  // fragment read offsets (shorts): chunk = kg ^ ((li>>1)&3)
  const int kxs  = (kg ^ ((li >> 1) & 3)) * 8;
  const int rdA  = (wr * 64 + li) * 32 + kxs;            // A region
  const int rdB  = 4096 + (wc * 64 + li) * 32 + kxs;     // B region (shorts)

  bf16x8 af[4], bq[4];
  f32x4 acc[4][4];
#pragma unroll
  for (int m = 0; m < 4; ++m)
#pragma unroll
    for (int n = 0; n < 4; ++n) acc[m][n] = f32x4{0.f, 0.f, 0.f, 0.f};

  // ---- prologue: stage tiles 0,1 into bufs 0,1; publish tile 0 ----
  STAGE(0, 0);
  STAGE(1, 24576);
  VMCNT(3);
  BAR();

  int cur = 0;   // buffer index of tile t
  for (int t = 0; t < NT; ++t) {
    int nx = cur + 2; if (nx >= 3) nx -= 3;
    const bool st2 = (t + 2 < NT);
    if (st2) STAGE(t + 2, nx * 24576);
    const unsigned short* base = &lds[cur * 12288];
#pragma unroll
    for (int mf = 0; mf < 4; ++mf)
      af[mf] = *reinterpret_cast<const bf16x8*>(base + rdA + mf * 512);
#pragma unroll
    for (int nf = 0; nf < 4; ++nf)
      bq[nf] = *reinterpret_cast<const bf16x8*>(base + rdB + nf * 512);
    if (st2) VMCNT(3); else VMCNT(0);
    BAR();
    __builtin_amdgcn_s_setprio(1);
#pragma unroll
    for (int mf = 0; mf < 4; ++mf)
#pragma unroll
      for (int nf = 0; nf < 4; ++nf)
        acc[mf][nf] = __builtin_amdgcn_mfma_f32_16x16x32_bf16(
            af[mf], bq[nf], acc[mf][nf], 0, 0, 0);
    __builtin_amdgcn_s_setprio(0);
    if (++cur == 3) cur = 0;
  }
#undef GLD
#undef STAGE
#undef BAR
#undef VMCNT

  // ---- epilogue: C/D layout col = li, row = kg*4 + j (m89-verified) ----
#pragma unroll
  for (int nf = 0; nf < 4; ++nf) {
    const int col = bCol + wc * 64 + nf * 16 + li;
    const float bv = bias[col];
#pragma unroll
    for (int mf = 0; mf < 4; ++mf) {
      const int row0 = bRow + wr * 64 + mf * 16 + kg * 4;
#pragma unroll
      for (int j = 0; j < 4; ++j)
        Y[(size_t)(row0 + j) * OUT_DIM + col] = acc[mf][nf][j] + bv;
    }
  }
}

extern "C" void kernel_launch(void* const* d_in, const int* in_sizes, int n_in,
                              void* d_out, int out_size, void* d_ws, size_t ws_size,
                              hipStream_t stream) {
  const float* x    = (const float*)d_in[0];
  const float* w    = (const float*)d_in[1];
  const float* bias = (const float*)d_in[2];
  const float* A    = (const float*)d_in[3];
  const float* B    = (const float*)d_in[4];
  float* y = (float*)d_out;

  const size_t xb_bytes = (size_t)M_DIM * IN_DIM * 2;          // 64 MiB
  const size_t wb_bytes = (size_t)OUT_DIM * IN_DIM * 2;        // 32 MiB
  if (ws_size < xb_bytes + wb_bytes) return;

  unsigned short* Xb = (unsigned short*)d_ws;
  unsigned short* Wb = (unsigned short*)((char*)d_ws + xb_bytes);

  prep_kernel<<<1536, 256, 0, stream>>>(x, Xb, w, A, B, Wb);
  gemm_kernel<<<(M_DIM / 128) * (OUT_DIM / 256), 512, 0, stream>>>(Xb, Wb, bias, y);
}

// Round 13
// 276.614 us; speedup vs baseline: 1.2343x; 1.1724x over previous
//
#include <hip/hip_runtime.h>

#define IN_DIM 4096
#define OUT_DIM 4096
#define M_DIM 8192
#define RANK 32
#define BK 64
#define NT (IN_DIM / BK)   // 64 K-tiles

typedef __bf16 bf16x8 __attribute__((ext_vector_type(8)));
typedef float f32x4 __attribute__((ext_vector_type(4)));

__device__ __forceinline__ unsigned short f2bf(float f) {
  unsigned u = __builtin_bit_cast(unsigned, f);
  u += 0x7FFF + ((u >> 16) & 1);   // round-to-nearest-even
  return (unsigned short)(u >> 16);
}

// ---------------- fused prep: blocks [0,1024) do Wb, [1024,1536) do Xb ----------------
__global__ __launch_bounds__(256) void prep_kernel(
    const float* __restrict__ X, unsigned short* __restrict__ Xb,
    const float* __restrict__ W, const float* __restrict__ A,
    const float* __restrict__ B, unsigned short* __restrict__ Wb) {
  const int tid = threadIdx.x;
  if (blockIdx.x >= 1024) {
    // ---- X cast path ----
    const int idx0 = (blockIdx.x - 1024) * 256 + tid;
    const int stride = 512 * 256;
    const int total4 = (M_DIM * IN_DIM) / 4;
    for (int i = idx0; i < total4; i += stride) {
      const float4 v = reinterpret_cast<const float4*>(X)[i];
      ushort4 o;
      o.x = f2bf(v.x); o.y = f2bf(v.y); o.z = f2bf(v.z); o.w = f2bf(v.w);
      reinterpret_cast<ushort4*>(Xb)[i] = o;
    }
    return;
  }
  // ---- W path: Wb = bf16(W + A @ B^T), rank-32 via one MFMA per fragment ----
  __shared__ unsigned short sA[128][40];
  __shared__ unsigned short sB[128][40];
  const int lane = tid & 63;
  const int wid  = tid >> 6;
  const int wr   = wid >> 1, wc = wid & 1;
  const int li   = lane & 15, kg = lane >> 4;
  const int bRow = (blockIdx.x >> 5) * 128;   // out dim
  const int bCol = (blockIdx.x & 31) * 128;   // in dim

  for (int i = tid; i < 128 * 8; i += 256) {
    const int r = i >> 3, q = i & 7;
    const float4 va = reinterpret_cast<const float4*>(A + (size_t)(bRow + r) * RANK)[q];
    ushort4 oa;
    oa.x = f2bf(va.x); oa.y = f2bf(va.y); oa.z = f2bf(va.z); oa.w = f2bf(va.w);
    *reinterpret_cast<ushort4*>(&sA[r][q * 4]) = oa;
    const float4 vb = reinterpret_cast<const float4*>(B + (size_t)(bCol + r) * RANK)[q];
    ushort4 ob;
    ob.x = f2bf(vb.x); ob.y = f2bf(vb.y); ob.z = f2bf(vb.z); ob.w = f2bf(vb.w);
    *reinterpret_cast<ushort4*>(&sB[r][q * 4]) = ob;
  }
  __syncthreads();

  bf16x8 af[4], bq[4];
#pragma unroll
  for (int m = 0; m < 4; ++m)
    af[m] = *reinterpret_cast<const bf16x8*>(&sA[wr * 64 + m * 16 + li][kg * 8]);
#pragma unroll
  for (int n = 0; n < 4; ++n)
    bq[n] = *reinterpret_cast<const bf16x8*>(&sB[wc * 64 + n * 16 + li][kg * 8]);

  f32x4 acc[4][4];
#pragma unroll
  for (int m = 0; m < 4; ++m)
#pragma unroll
    for (int n = 0; n < 4; ++n) {
      acc[m][n] = f32x4{0.f, 0.f, 0.f, 0.f};
      acc[m][n] = __builtin_amdgcn_mfma_f32_16x16x32_bf16(af[m], bq[n], acc[m][n], 0, 0, 0);
    }

#pragma unroll
  for (int m = 0; m < 4; ++m) {
#pragma unroll
    for (int n = 0; n < 4; ++n) {
      const int col = bCol + wc * 64 + n * 16 + li;
#pragma unroll
      for (int j = 0; j < 4; ++j) {
        const int row = bRow + wr * 64 + m * 16 + kg * 4 + j;
        const size_t idx = (size_t)row * IN_DIM + col;
        Wb[idx] = f2bf(W[idx] + acc[m][n][j]);
      }
    }
  }
}

// ---------------- main GEMM: 256x256 tile, BK=64, 4-phase, ONE barrier/phase ----------------
// Campaign-best structure (R6). R7-R12 tested: fragment prefetch, sched_barrier
// pinning, MFMA-leading SGB, DS-leading SGB + peeled branch-free loop, 2-blocks/CU
// TLP (two geometries) — all null or negative. 256²/BK=64 minimizes LDS bytes
// per FLOP (24 B/kFLOP); within-block LDS→MFMA serialization (~1074 cyc/window
// = 621 MFMA + ~450 exposed LDS) is the plateau at HIP-source level.
//   ph0: [STAGE_B(t+1,1); STAGE_A(t+1,1)] RD_A(0),RD_B(0) | BAR | MM(0,0)
//   ph1:                                   RD_B(1)         | BAR | MM(0,1)
//   ph2: [STAGE_A(t+2,0)]                  RD_A(1)         | BAR | MM(1,0)
//   ph3: [STAGE_B(t+2,0)] vmcnt(4)                         | BAR | MM(1,1)
// WAR: stage-write to region R >=1 barrier after the MM that lgkm-waits R's
// last read. vmcnt: 8 issued/tile; queue at ph3 = 12; vmcnt(4) retires exactly
// tile t+1's 8 loads. Never drains to 0 in steady state.
__global__ __launch_bounds__(512, 2) void gemm_kernel(
    const unsigned short* __restrict__ Xb, const unsigned short* __restrict__ Wb,
    const float* __restrict__ bias, float* __restrict__ Y) {
  __shared__ unsigned short lds[8][8192];   // 128 KiB
  const int tid  = threadIdx.x;
  const int lane = tid & 63;
  const int wid  = tid >> 6;          // 0..7
  const int wr   = wid >> 2;          // 0..1
  const int wc   = wid & 3;           // 0..3
  const int li   = lane & 15, kg = lane >> 4;

  // XCD-aware bijective swizzle: 512 blocks = 8 XCDs x 64
  const int bid = blockIdx.x;
  const int swz = (bid & 7) * 64 + (bid >> 3);
  const int bx  = swz & 15;           // N tiles: 4096/256 = 16
  const int by  = swz >> 4;           // M tiles: 8192/256 = 32
  const int bRow = by * 256, bCol = bx * 256;

  // staging: physical chunk p = l*512 + tid; local row r = p>>3; kc = (p&7)^(r&7)
  const int kcS = (tid & 7) ^ ((tid >> 3) & 7);
  const unsigned short* srcA[2][2];
  const unsigned short* srcB[2][2];
#pragma unroll
  for (int h = 0; h < 2; ++h)
#pragma unroll
    for (int l = 0; l < 2; ++l) {
      const int gA = l * 128 + h * 64 + (tid >> 3);
      const int gB = (l * 2 + (tid >> 8)) * 64 + h * 32 + ((tid >> 3) & 31);
      srcA[h][l] = Xb + (size_t)(bRow + gA) * IN_DIM + kcS * 8;
      srcB[h][l] = Wb + (size_t)(bCol + gB) * IN_DIM + kcS * 8;
    }
  char* const ldsRaw = (char*)&lds[0][0];

#define GLD(src, dstoff)                                                       \
  __builtin_amdgcn_global_load_lds(                                            \
      (const __attribute__((address_space(1))) unsigned int*)(src),            \
      (__attribute__((address_space(3))) unsigned int*)(ldsRaw + (dstoff)),    \
      16, 0, 0)
#define STAGE_A(s, h)                                                          \
  do {                                                                         \
    const int q_ = (((s) & 1) << 2) + (h);                                     \
    GLD(srcA[h][0] + (s) * BK, q_ * 16384 + tid * 16);                         \
    GLD(srcA[h][1] + (s) * BK, q_ * 16384 + 8192 + tid * 16);                  \
  } while (0)
#define STAGE_B(s, h)                                                          \
  do {                                                                         \
    const int q_ = (((s) & 1) << 2) + 2 + (h);                                 \
    GLD(srcB[h][0] + (s) * BK, q_ * 16384 + tid * 16);                         \
    GLD(srcB[h][1] + (s) * BK, q_ * 16384 + 8192 + tid * 16);                  \
  } while (0)
#define BAR() __builtin_amdgcn_s_barrier()

  // fragment read addressing (conflict-free: bank-quad = (ks*4+kg)^(li&7)
  // covers all 8 quads per 16-lane group)
  const int rowAoff = (wr * 64 + li) * 64;
  const int rowBoff = (wc * 32 + li) * 64;
  int kx[2];
  kx[0] = ((0 * 4 + kg) ^ (li & 7)) * 8;
  kx[1] = ((1 * 4 + kg) ^ (li & 7)) * 8;

  bf16x8 af[4][2], bq[4][2];
  f32x4 acc[8][4];
#pragma unroll
  for (int m = 0; m < 8; ++m)
#pragma unroll
    for (int n = 0; n < 4; ++n) acc[m][n] = f32x4{0.f, 0.f, 0.f, 0.f};

#define RD_A(ms_)                                                              \
  do {                                                                         \
    const unsigned short* b_ = &lds[(dcur << 2) + (ms_)][0] + rowAoff;         \
    _Pragma("unroll") for (int mq = 0; mq < 4; ++mq)                           \
      _Pragma("unroll") for (int ks = 0; ks < 2; ++ks)                         \
        af[mq][ks] =                                                           \
            *reinterpret_cast<const bf16x8*>(b_ + mq * 1024 + kx[ks]);         \
  } while (0)
#define RD_B(ns_)                                                              \
  do {                                                                         \
    const unsigned short* b_ = &lds[(dcur << 2) + 2 + (ns_)][0] + rowBoff;     \
    _Pragma("unroll") for (int nq = 0; nq < 2; ++nq)                           \
      _Pragma("unroll") for (int ks = 0; ks < 2; ++ks)                         \
        bq[(ns_) * 2 + nq][ks] =                                               \
            *reinterpret_cast<const bf16x8*>(b_ + nq * 1024 + kx[ks]);         \
  } while (0)
#define MM(ms_, ns_)                                                           \
  do {                                                                         \
    __builtin_amdgcn_s_setprio(1);                                             \
    _Pragma("unroll") for (int mq = 0; mq < 4; ++mq)                           \
      _Pragma("unroll") for (int nq = 0; nq < 2; ++nq)                         \
        _Pragma("unroll") for (int ks = 0; ks < 2; ++ks)                       \
          acc[(ms_) * 4 + mq][(ns_) * 2 + nq] =                                \
              __builtin_amdgcn_mfma_f32_16x16x32_bf16(                         \
                  af[mq][ks], bq[(ns_) * 2 + nq][ks],                          \
                  acc[(ms_) * 4 + mq][(ns_) * 2 + nq], 0, 0, 0);               \
    __builtin_amdgcn_s_setprio(0);                                             \
  } while (0)

  // ---- prologue: tile 0 (8 loads) + A0,B0 of tile 1 (4 loads); drain tile 0 ----
  STAGE_A(0, 0); STAGE_B(0, 0); STAGE_A(0, 1); STAGE_B(0, 1);
  STAGE_A(1, 0); STAGE_B(1, 0);
  asm volatile("s_waitcnt vmcnt(4)" ::: "memory");
  BAR();

  for (int t = 0; t < NT; ++t) {
    const int dcur = t & 1;
    const bool st1 = (t + 1 < NT), st2 = (t + 2 < NT);
    // ph0
    if (st1) { STAGE_B(t + 1, 1); STAGE_A(t + 1, 1); }
    RD_A(0); RD_B(0);
    BAR();
    MM(0, 0);
    // ph1
    RD_B(1);
    BAR();
    MM(0, 1);
    // ph2
    if (st2) STAGE_A(t + 2, 0);
    RD_A(1);
    BAR();
    MM(1, 0);
    // ph3
    if (st2) {
      STAGE_B(t + 2, 0);
      asm volatile("s_waitcnt vmcnt(4)" ::: "memory");
    } else {
      asm volatile("s_waitcnt vmcnt(0)" ::: "memory");
    }
    BAR();
    MM(1, 1);
  }
#undef GLD
#undef STAGE_A
#undef STAGE_B
#undef RD_A
#undef RD_B
#undef MM
#undef BAR

  // ---- epilogue: C/D layout col = li, row = kg*4 + j (m89-verified) ----
#pragma unroll
  for (int nf = 0; nf < 4; ++nf) {
    const int col = bCol + wc * 64 + nf * 16 + li;
    const float bv = bias[col];
#pragma unroll
    for (int mf = 0; mf < 8; ++mf) {
      const int row0 = bRow + wr * 128 + mf * 16 + kg * 4;
#pragma unroll
      for (int j = 0; j < 4; ++j)
        Y[(size_t)(row0 + j) * OUT_DIM + col] = acc[mf][nf][j] + bv;
    }
  }
}

extern "C" void kernel_launch(void* const* d_in, const int* in_sizes, int n_in,
                              void* d_out, int out_size, void* d_ws, size_t ws_size,
                              hipStream_t stream) {
  const float* x    = (const float*)d_in[0];
  const float* w    = (const float*)d_in[1];
  const float* bias = (const float*)d_in[2];
  const float* A    = (const float*)d_in[3];
  const float* B    = (const float*)d_in[4];
  float* y = (float*)d_out;

  const size_t xb_bytes = (size_t)M_DIM * IN_DIM * 2;          // 64 MiB
  const size_t wb_bytes = (size_t)OUT_DIM * IN_DIM * 2;        // 32 MiB
  if (ws_size < xb_bytes + wb_bytes) return;

  unsigned short* Xb = (unsigned short*)d_ws;
  unsigned short* Wb = (unsigned short*)((char*)d_ws + xb_bytes);

  prep_kernel<<<1536, 256, 0, stream>>>(x, Xb, w, A, B, Wb);
  gemm_kernel<<<(M_DIM / 256) * (OUT_DIM / 256), 512, 0, stream>>>(Xb, Wb, bias, y);
}